// Round 1
// 190.017 us; speedup vs baseline: 1.0096x; 1.0096x over previous
//
#include <hip/hip_runtime.h>

// PlateYoloBlock: (32,13,256,256) fp32 -> (32,65536,13) fp32
// out[b][y*256+x][c]:
//   c=0: (sigmoid(v)+x)*8   c=1: (sigmoid(v)+y)*8
//   c=2,3: exp(v)*8         c=4..11: v*8          c=12: sigmoid(v)
//
// v2: vectorize the GLOBAL LOADS (the v1 bottleneck — scalar dword reads
// plateau at ~2.5-3 TB/s on gfx950; float4 streams hit ~6.3 TB/s).
// Each thread owns 4 consecutive positions -> 13 global_load_dwordx4.
// Its 52 results are CONTIGUOUS in the output layout (floats 52*tid..+51),
// so LDS staging becomes 13 ds_write_b128 at 52-dword lane stride:
// start banks for lanes 0..7 = {0,20,8,28,16,4,24,12}, each b128 covering
// 4 consecutive banks -> all 32 banks hit exactly once per 8-lane phase
// -> conflict-free. Copy-out stays the linear float4 stream (0 conflicts).

#define NB      32
#define NC      13
#define HW      65536     // 256*256 positions per batch
#define WIDTH   256
#define TILE    1024      // positions per block (divides HW; whole tile in one batch)
#define THREADS 256
#define PPT     4         // positions per thread (float4 load width)

__device__ __forceinline__ float sigmoidf_(float x) {
    return 1.0f / (1.0f + __expf(-x));
}

__global__ __launch_bounds__(THREADS) void plate_yolo_kernel(
        const float* __restrict__ in, float* __restrict__ out) {
    __shared__ float lds[TILE * NC];   // 53,248 B -> 3 blocks/CU (12 waves/CU)

    const int tid = threadIdx.x;
    const long long s0 = (long long)blockIdx.x * TILE;   // global spatial base
    const int b = (int)(s0 >> 16);                       // 65536 positions/batch
    const int posBase = (int)(s0 & (HW - 1));
    const float* __restrict__ inB = in + (long long)b * NC * HW + posBase;

    const int p0   = tid * PPT;          // local position base, 4 consecutive
    const int pos0 = posBase + p0;       // posBase multiple of 1024, p0 mult of 4
    const float fx0 = (float)(pos0 & (WIDTH - 1));  // row never crossed in a quad
    const float fy  = (float)(pos0 >> 8);

    // Phase A: issue all 13 float4 loads up front (max bytes in flight).
    float4 v[NC];
    #pragma unroll
    for (int c = 0; c < NC; ++c) {
        v[c] = *(const float4*)(inB + c * HW + p0);
    }

    // Phase B: pointwise math, scattered into output-layout register block.
    float res[PPT * NC];                 // res[q*13 + c], all indices static
    #pragma unroll
    for (int c = 0; c < NC; ++c) {
        const float xs[4] = { v[c].x, v[c].y, v[c].z, v[c].w };
        #pragma unroll
        for (int q = 0; q < PPT; ++q) {
            const float x = xs[q];
            float r;
            if (c == 0)                 r = (sigmoidf_(x) + (fx0 + (float)q)) * 8.0f;
            else if (c == 1)            r = (sigmoidf_(x) + fy) * 8.0f;
            else if (c == 2 || c == 3)  r = __expf(x) * 8.0f;
            else if (c == 12)           r = sigmoidf_(x);
            else                        r = x * 8.0f;
            res[q * NC + c] = r;
        }
    }

    // Phase C: 13 ds_write_b128 into the thread's contiguous 52-float region.
    // Byte base = tid*208 (16B aligned); conflict-free per the bank analysis.
    float4* __restrict__ ldsT = (float4*)(lds + p0 * NC);
    #pragma unroll
    for (int j = 0; j < NC; ++j) {
        ldsT[j] = make_float4(res[4*j + 0], res[4*j + 1],
                              res[4*j + 2], res[4*j + 3]);
    }
    __syncthreads();

    // Phase D: contiguous float4 copy-out (ds_read_b128 + global_store_dwordx4).
    // TILE*NC/4 = 3328 = 13*256 float4s; tile base byte offset = blk*53248 (16B-aligned).
    const float4* __restrict__ src = (const float4*)lds;
    float4* __restrict__ dst = (float4*)(out + s0 * NC);
    #pragma unroll
    for (int j = 0; j < NC; ++j) {
        dst[tid + j * THREADS] = src[tid + j * THREADS];
    }
}

extern "C" void kernel_launch(void* const* d_in, const int* in_sizes, int n_in,
                              void* d_out, int out_size, void* d_ws, size_t ws_size,
                              hipStream_t stream) {
    const float* in = (const float*)d_in[0];
    float* out = (float*)d_out;
    const int blocks = (NB * HW) / TILE;   // 2048
    plate_yolo_kernel<<<blocks, THREADS, 0, stream>>>(in, out);
}